// Round 1
// baseline (133.338 us; speedup 1.0000x reference)
//
#include <hip/hip_runtime.h>

#define GAT_H 12
#define GAT_N 4096
#define GAT_F 64
#define LOG2E 1.4426950408889634f

// Prep: blocks 0..11 compute s_h = <W_h, a_src_h>, d_h = <W_h, a_dst_h>.
// Block 12 computes mean(x) (fallback for neighborless rows -> uniform attn).
__global__ __launch_bounds__(64) void gat_prep(const float* __restrict__ W,
                                               const float* __restrict__ a,
                                               const float* __restrict__ x,
                                               float* __restrict__ sd) {
    const int b = blockIdx.x;
    const int f = threadIdx.x;
    if (b < GAT_H) {
        const float wf = W[b * GAT_F + f];
        float ps = wf * a[b * 2 * GAT_F + f];
        float pd = wf * a[b * 2 * GAT_F + GAT_F + f];
        #pragma unroll
        for (int off = 32; off > 0; off >>= 1) {
            ps += __shfl_xor(ps, off, 64);
            pd += __shfl_xor(pd, off, 64);
        }
        if (f == 0) { sd[b] = ps; sd[GAT_H + b] = pd; }
    } else {
        float s = 0.0f;
        #pragma unroll
        for (int j = 0; j < GAT_N / 64; ++j) s += x[j * 64 + f];
        #pragma unroll
        for (int off = 32; off > 0; off >>= 1) s += __shfl_xor(s, off, 64);
        if (f == 0) sd[2 * GAT_H] = s * (1.0f / GAT_N);
    }
}

// Main: one wave per row i. Lanes split j (4 j's per lane per iter via int4).
// For each (i,j,h): e = lrelu(x_i*s_h + x_j*d_h); masked softmax over j,
// accumulating denom_h and num_h = sum attn-weight * x_j.
// No max-subtraction needed: |scores| <= ~3, exp2 args in [-5,5].
__global__ __launch_bounds__(256) void gat_main(const float* __restrict__ x,
                                                const int* __restrict__ adj,
                                                const float* __restrict__ W,
                                                const float* __restrict__ sd,
                                                float* __restrict__ out) {
    __shared__ float xs[GAT_N];
    const int tid = threadIdx.x;
    #pragma unroll
    for (int it = 0; it < GAT_N / (256 * 4); ++it) {
        ((float4*)xs)[it * 256 + tid] = ((const float4*)x)[it * 256 + tid];
    }
    __syncthreads();

    const int lane = tid & 63;
    const int wave = tid >> 6;
    const int row  = blockIdx.x * 4 + wave;
    const float xi = xs[row];

    float b1[GAT_H], d1[GAT_H];
    #pragma unroll
    for (int h = 0; h < GAT_H; ++h) {
        b1[h] = xi * sd[h] * LOG2E;          // x_i * s_h * log2(e)
        d1[h] = sd[GAT_H + h] * LOG2E;       // d_h * log2(e)
    }
    float den[GAT_H], num[GAT_H];
    #pragma unroll
    for (int h = 0; h < GAT_H; ++h) { den[h] = 0.0f; num[h] = 0.0f; }

    const int4*   __restrict__ adjrow = (const int4*)(adj + (size_t)row * GAT_N);
    const float4* __restrict__ xs4    = (const float4*)xs;

    int4   a4 = adjrow[lane];
    float4 x4 = xs4[lane];
    #pragma unroll 1
    for (int it = 0; it < 16; ++it) {
        const int nxt = (it < 15 ? it + 1 : 15) * 64 + lane;  // clamped prefetch
        int4   a4n = adjrow[nxt];
        float4 x4n = xs4[nxt];
        #pragma unroll
        for (int e = 0; e < 4; ++e) {
            const int   ai = (e == 0) ? a4.x : (e == 1) ? a4.y : (e == 2) ? a4.z : a4.w;
            const float xj = (e == 0) ? x4.x : (e == 1) ? x4.y : (e == 2) ? x4.z : x4.w;
            const bool msk = ai > 0;
            #pragma unroll
            for (int h = 0; h < GAT_H; ++h) {
                float q   = fmaf(xj, d1[h], b1[h]);       // log2e * (x_i s + x_j d)
                float arg = fmaxf(q, 0.2f * q);           // lrelu commutes w/ +scale
                arg = msk ? arg : -12800.0f;              // exp2 -> exact 0
                float p = __builtin_amdgcn_exp2f(arg);
                den[h] += p;
                num[h] = fmaf(p, xj, num[h]);
            }
        }
        a4 = a4n; x4 = x4n;
    }

    #pragma unroll
    for (int h = 0; h < GAT_H; ++h) {
        #pragma unroll
        for (int off = 32; off > 0; off >>= 1) {
            den[h] += __shfl_xor(den[h], off, 64);
            num[h] += __shfl_xor(num[h], off, 64);
        }
    }

    const float xmean = sd[2 * GAT_H];
    const size_t base = (size_t)row * (GAT_H * GAT_F);
    #pragma unroll
    for (int h = 0; h < GAT_H; ++h) {
        const float c = den[h] > 0.0f ? num[h] / den[h] : xmean;
        out[base + h * GAT_F + lane] = c * W[h * GAT_F + lane];
    }
}

extern "C" void kernel_launch(void* const* d_in, const int* in_sizes, int n_in,
                              void* d_out, int out_size, void* d_ws, size_t ws_size,
                              hipStream_t stream) {
    const float* x   = (const float*)d_in[0];
    const int*   adj = (const int*)d_in[1];
    const float* W   = (const float*)d_in[2];
    const float* a   = (const float*)d_in[3];
    float* out = (float*)d_out;
    float* sd  = (float*)d_ws;   // 25 floats: s[12], d[12], mean(x)

    gat_prep<<<13, 64, 0, stream>>>(W, a, x, sd);
    gat_main<<<GAT_N / 4, 256, 0, stream>>>(x, adj, W, sd, out);
}

// Round 2
// 127.717 us; speedup vs baseline: 1.0440x; 1.0440x over previous
//
#include <hip/hip_runtime.h>

#define GAT_H 12
#define GAT_N 4096
#define GAT_F 64
#define GAT_HALF 2048
#define LOG2E 1.4426950408889634f

// Prep: blocks 0..11 compute s_h = <W_h, a_src_h>, d_h = <W_h, a_dst_h>.
// Block 12 computes mean(x) (fallback for neighborless rows -> uniform attn).
__global__ __launch_bounds__(64) void gat_prep(const float* __restrict__ W,
                                               const float* __restrict__ a,
                                               const float* __restrict__ x,
                                               float* __restrict__ sd) {
    const int b = blockIdx.x;
    const int f = threadIdx.x;
    if (b < GAT_H) {
        const float wf = W[b * GAT_F + f];
        float ps = wf * a[b * 2 * GAT_F + f];
        float pd = wf * a[b * 2 * GAT_F + GAT_F + f];
        #pragma unroll
        for (int off = 32; off > 0; off >>= 1) {
            ps += __shfl_xor(ps, off, 64);
            pd += __shfl_xor(pd, off, 64);
        }
        if (f == 0) { sd[b] = ps; sd[GAT_H + b] = pd; }
    } else {
        float s = 0.0f;
        #pragma unroll
        for (int j = 0; j < GAT_N / 64; ++j) s += x[j * 64 + f];
        #pragma unroll
        for (int off = 32; off > 0; off >>= 1) s += __shfl_xor(s, off, 64);
        if (f == 0) sd[2 * GAT_H] = s * (1.0f / GAT_N);
    }
}

// Main: 2 rows per block, 2 waves per row (each wave does half the j range).
// Inner loop per (element, h): 5 VALU + 1 exp2.
//   q   = log2e*(x_i s_h + x_j d_h)                 [fma]
//   t   = 0.6*q + mb   (mb = adj?0:-12800)          [fma, mask folded in]
//   arg = 0.4*|q| + t  (= lrelu(q) + mb; abs free)  [fma]
//   p   = exp2(arg)    (masked -> exact 0)          [trans]
//   den += p; num += p*x_j                          [add, fma]
__global__ __launch_bounds__(256) void gat_main(const float* __restrict__ x,
                                                const int* __restrict__ adj,
                                                const float* __restrict__ W,
                                                const float* __restrict__ sd,
                                                float* __restrict__ out) {
    __shared__ float xs[GAT_N];
    __shared__ float part[2][2][GAT_H][2];   // [row-in-block][half][h][den,num]
    __shared__ float cbuf[2][GAT_H];

    const int tid = threadIdx.x;
    #pragma unroll
    for (int it = 0; it < GAT_N / (256 * 4); ++it) {
        ((float4*)xs)[it * 256 + tid] = ((const float4*)x)[it * 256 + tid];
    }
    __syncthreads();

    const int lane = tid & 63;
    const int wave = tid >> 6;
    const int rloc = wave >> 1;          // 0..1  row within block
    const int half = wave & 1;           // 0..1  j-half
    const int row  = blockIdx.x * 2 + rloc;
    const float xi = xs[row];

    float b1[GAT_H], d1[GAT_H];
    #pragma unroll
    for (int h = 0; h < GAT_H; ++h) {
        b1[h] = xi * sd[h] * LOG2E;
        d1[h] = sd[GAT_H + h] * LOG2E;
    }
    float den[GAT_H], num[GAT_H];
    #pragma unroll
    for (int h = 0; h < GAT_H; ++h) { den[h] = 0.0f; num[h] = 0.0f; }

    const int4*   __restrict__ adjrow =
        (const int4*)(adj + (size_t)row * GAT_N + half * GAT_HALF);
    const float4* __restrict__ xs4 = (const float4*)(xs + half * GAT_HALF);

    int4   a4 = adjrow[lane];
    float4 x4 = xs4[lane];
    #pragma unroll 1
    for (int it = 0; it < 8; ++it) {
        const int nxt = (it < 7 ? it + 1 : 7) * 64 + lane;   // clamped prefetch
        int4   a4n = adjrow[nxt];
        float4 x4n = xs4[nxt];
        #pragma unroll
        for (int e = 0; e < 4; ++e) {
            const int   ai = (e == 0) ? a4.x : (e == 1) ? a4.y : (e == 2) ? a4.z : a4.w;
            const float xj = (e == 0) ? x4.x : (e == 1) ? x4.y : (e == 2) ? x4.z : x4.w;
            const float mb = (ai > 0) ? 0.0f : -12800.0f;    // cmp + cndmask, once/elem
            #pragma unroll
            for (int h = 0; h < GAT_H; ++h) {
                const float q   = fmaf(xj, d1[h], b1[h]);
                const float t   = fmaf(0.6f, q, mb);
                const float arg = fmaf(0.4f, fabsf(q), t);   // lrelu + mask bias
                const float p   = __builtin_amdgcn_exp2f(arg);
                den[h] += p;
                num[h] = fmaf(p, xj, num[h]);
            }
        }
        a4 = a4n; x4 = x4n;
    }

    #pragma unroll
    for (int h = 0; h < GAT_H; ++h) {
        #pragma unroll
        for (int off = 32; off > 0; off >>= 1) {
            den[h] += __shfl_xor(den[h], off, 64);
            num[h] += __shfl_xor(num[h], off, 64);
        }
    }
    if (lane == 0) {
        #pragma unroll
        for (int h = 0; h < GAT_H; ++h) {
            part[rloc][half][h][0] = den[h];
            part[rloc][half][h][1] = num[h];
        }
    }
    __syncthreads();

    if (tid < 2 * GAT_H) {
        const int r = (tid >= GAT_H) ? 1 : 0;
        const int h = tid - r * GAT_H;
        const float dsum = part[r][0][h][0] + part[r][1][h][0];
        const float nsum = part[r][0][h][1] + part[r][1][h][1];
        cbuf[r][h] = dsum > 0.0f ? nsum / dsum : sd[2 * GAT_H];
    }
    __syncthreads();

    // Epilogue: out[row][h*64+f] = c[row][h] * W[h*64+f]; pos == h*64+f.
    #pragma unroll
    for (int r = 0; r < 2; ++r) {
        const size_t base = (size_t)(blockIdx.x * 2 + r) * (GAT_H * GAT_F);
        #pragma unroll
        for (int k = 0; k < 3; ++k) {
            const int pos = k * 256 + tid;
            out[base + pos] = cbuf[r][pos >> 6] * W[pos];
        }
    }
}

extern "C" void kernel_launch(void* const* d_in, const int* in_sizes, int n_in,
                              void* d_out, int out_size, void* d_ws, size_t ws_size,
                              hipStream_t stream) {
    const float* x   = (const float*)d_in[0];
    const int*   adj = (const int*)d_in[1];
    const float* W   = (const float*)d_in[2];
    const float* a   = (const float*)d_in[3];
    float* out = (float*)d_out;
    float* sd  = (float*)d_ws;   // 25 floats: s[12], d[12], mean(x)

    gat_prep<<<13, 64, 0, stream>>>(W, a, x, sd);
    gat_main<<<GAT_N / 2, 256, 0, stream>>>(x, adj, W, sd, out);
}